// Round 7
// baseline (282.768 us; speedup 1.0000x reference)
//
#include <hip/hip_runtime.h>

typedef __bf16 bf16x8 __attribute__((ext_vector_type(8)));
typedef float floatx4 __attribute__((ext_vector_type(4)));

#define DEVI __device__ __forceinline__

DEVI unsigned short f2bf(float f) {
  union { float f; unsigned u; } v; v.f = f;
  unsigned r = v.u + 0x7FFFu + ((v.u >> 16) & 1u);
  return (unsigned short)(r >> 16);
}

DEVI void gload_lds16(const void* g, void* l) {
  __builtin_amdgcn_global_load_lds((const __attribute__((address_space(1))) void*)g,
                                   (__attribute__((address_space(3))) void*)l,
                                   16, 0, 0);
}

// ---- transpose-convert x[B,512,2048] f32 -> xt[B,2048,512] bf16 ; z==16 slice does weight prep ----
__global__ __launch_bounds__(256) void k_transpose(
    const float* __restrict__ x, unsigned short* __restrict__ xt,
    const float* __restrict__ phi_w, const float* __restrict__ g_w,
    const float* __restrict__ theta_w, const float* __restrict__ W_w,
    const float* __restrict__ phi_b, const float* __restrict__ g_b,
    unsigned short* __restrict__ wpg, unsigned short* __restrict__ thw,
    unsigned short* __restrict__ ww, float* __restrict__ pgbias) {
  const int t = threadIdx.x;
  if (blockIdx.z == 16) {
    const int T0 = 512 * 512, T1 = T0 + 256 * 512, T2 = T1 + 512 * 256, T3 = T2 + 512;
    int base = (blockIdx.y * 32 + blockIdx.x) * 256 + t;
    for (int i = base; i < T3; i += 65536) {
      if (i < T0) {
        int o = i >> 9, c = i & 511;
        float v = (o < 256) ? phi_w[o * 512 + c] : g_w[(o - 256) * 512 + c];
        wpg[i] = f2bf(v);
      } else if (i < T1) {
        int j = i - T0; thw[j] = f2bf(theta_w[j]);
      } else if (i < T2) {
        int j = i - T1; ww[j] = f2bf(W_w[j]);
      } else {
        int o = i - T2; pgbias[o] = (o < 256) ? phi_b[o] : g_b[o - 256];
      }
    }
    return;
  }
  __shared__ float tile[64][65];
  const int b = blockIdx.z, c0 = blockIdx.y * 64, n0 = blockIdx.x * 64;
  const float* xb = x + (size_t)b * 512 * 2048;
#pragma unroll
  for (int i = 0; i < 16; ++i) {
    int lin = i * 256 + t;
    int lc = lin >> 6, ln = lin & 63;
    tile[lc][ln] = xb[(size_t)(c0 + lc) * 2048 + (n0 + ln)];
  }
  __syncthreads();
  unsigned short* xtb = xt + (size_t)b * 2048 * 512;
#pragma unroll
  for (int i = 0; i < 16; ++i) {
    int lin = i * 256 + t;
    int ln = lin >> 6, lc = lin & 63;
    xtb[(size_t)(n0 + ln) * 512 + (c0 + lc)] = f2bf(tile[lc][ln]);
  }
}

// ================= 256x256 8-phase GEMM body (T3+T4+T5) =================
// C[i,j] = scale * sum_k A[i,k]B[j,k] (+bias). 512 threads = 8 waves (2Mx4N),
// wave-tile 128x64. BK=64 split in two 32-k "units". LDS ring of 4 units x
// 32 KB = 128 KiB. Unit: 512 rows (256 A + 256 B) x 32 bf16; 16B slot s of row
// r holds k-sub (s ^ ((r>>1)&3)) -> <=2-way bank aliasing (free). Staged via
// global_load_lds, pre-swizzled source, linear dest (rule 21). vmcnt(4) at
// phases 1 & 3 only; raw s_barrier; lgkmcnt(0)+sched_barrier before MFMA.

#define VMC4 asm volatile("s_waitcnt vmcnt(4)" ::: "memory");
#define VMC0 asm volatile("s_waitcnt vmcnt(0)" ::: "memory");
#define VMNO

#define PHASE(RING, MH, SR, SK, C0, VM)                                          \
  {                                                                              \
    bf16x8 af[4], bq[4];                                                         \
    _Pragma("unroll") for (int m = 0; m < 4; ++m) {                              \
      int ra = wr * 128 + ((MH) * 4 + m) * 16 + l16;                             \
      af[m] = *(const bf16x8*)(lds + ((RING) << 15) + ra * 64 +                  \
                               ((lq << 4) ^ (((ra >> 1) & 3) << 4)));            \
    }                                                                            \
    _Pragma("unroll") for (int n = 0; n < 4; ++n) {                              \
      int rb = 256 + wc * 64 + n * 16 + l16;                                     \
      bq[n] = *(const bf16x8*)(lds + ((RING) << 15) + rb * 64 +                  \
                               ((lq << 4) ^ (((rb >> 1) & 3) << 4)));            \
    }                                                                            \
    if ((SR) >= 0) {                                                             \
      stage_chunk((SR), (SK), kt + 1, (C0));                                     \
      stage_chunk((SR), (SK), kt + 1, (C0) + 1);                                 \
    }                                                                            \
    VM                                                                           \
    __builtin_amdgcn_s_barrier();                                                \
    asm volatile("s_waitcnt lgkmcnt(0)" ::: "memory");                           \
    __builtin_amdgcn_sched_barrier(0);                                           \
    __builtin_amdgcn_s_setprio(1);                                               \
    _Pragma("unroll") for (int m = 0; m < 4; ++m)                                \
      _Pragma("unroll") for (int n = 0; n < 4; ++n)                              \
        acc[(MH) * 4 + m][n] = __builtin_amdgcn_mfma_f32_16x16x32_bf16(          \
            af[m], bq[n], acc[(MH) * 4 + m][n], 0, 0, 0);                        \
    __builtin_amdgcn_s_setprio(0);                                               \
    __builtin_amdgcn_s_barrier();                                                \
  }

template <int EPI, bool F32OUT>
DEVI void gemm256_body(const unsigned short* __restrict__ Ap,
                       const unsigned short* __restrict__ Bp,
                       void* __restrict__ Cp, int ldc, int K, int k0, int nt,
                       int row0, int col0, const float* __restrict__ bias,
                       float scale, char* lds) {
  const int t = threadIdx.x;
  const int w = t >> 6, l = t & 63;
  const int l16 = l & 15, lq = l >> 4;
  const int wr = w >> 2, wc = w & 3;

  floatx4 acc[8][4];
#pragma unroll
  for (int m = 0; m < 8; ++m)
#pragma unroll
    for (int n = 0; n < 4; ++n) acc[m][n] = (floatx4){0.f, 0.f, 0.f, 0.f};

  auto stage_chunk = [&](int ring, int kk, int skt, int c) {
    int row = (c * 8 + w) * 16 + (l >> 2);  // 0..511: 0-255 A rows, 256-511 B rows
    int slot = l & 3;
    int ksub = slot ^ ((row >> 1) & 3);
    int kcol = k0 + (skt << 6) + (kk << 5) + (ksub << 3);
    const unsigned short* src = (row < 256)
        ? Ap + (size_t)(row0 + row) * K + kcol
        : Bp + (size_t)(col0 + row - 256) * K + kcol;
    gload_lds16(src, lds + (ring << 15) + (((c * 8 + w) << 6) + l) * 16);
  };

  // prologue: stage units 0 (kk=0) and 1 (kk=1) of K-tile 0; wait unit0.
#pragma unroll
  for (int c = 0; c < 4; ++c) stage_chunk(0, 0, 0, c);
#pragma unroll
  for (int c = 0; c < 4; ++c) stage_chunk(1, 1, 0, c);
  VMC4
  __builtin_amdgcn_s_barrier();

  for (int kt = 0; kt < nt; ++kt) {
    const int r0 = (2 * kt) & 3, r1 = (2 * kt + 1) & 3;
    const int s0 = (2 * kt + 2) & 3, s1 = (2 * kt + 3) & 3;
    if (kt + 1 < nt) {
      PHASE(r0, 0, s0, 0, 0, VMNO)   // p0: stage next-even chunks 0,1
      PHASE(r0, 1, s0, 0, 2, VMC4)   // p1: vmcnt(4) -> unit r1 ready
      PHASE(r1, 0, s1, 1, 0, VMNO)   // p2: stage next-odd chunks 0,1
      PHASE(r1, 1, s1, 1, 2, VMC4)   // p3: vmcnt(4) -> next even unit ready
    } else {
      PHASE(r0, 0, -1, 0, 0, VMNO)
      PHASE(r0, 1, -1, 0, 0, VMC0)   // drain: unit r1 ready
      PHASE(r1, 0, -1, 0, 0, VMNO)
      PHASE(r1, 1, -1, 0, 0, VMNO)
    }
  }

#pragma unroll
  for (int m = 0; m < 8; ++m)
#pragma unroll
    for (int n = 0; n < 4; ++n) {
      int gc = col0 + wc * 64 + n * 16 + l16;
      float bc = (EPI == 2) ? bias[gc] : 0.f;
#pragma unroll
      for (int r = 0; r < 4; ++r) {
        int gr = row0 + wr * 128 + m * 16 + lq * 4 + r;
        float v = acc[m][n][r] * scale;
        if (EPI == 1) v += bias[gr];
        if (EPI == 2) v += bc;
        if (F32OUT)
          ((float*)Cp)[(size_t)gr * ldc + gc] = v;
        else
          ((unsigned short*)Cp)[(size_t)gr * ldc + gc] = f2bf(v);
      }
    }
}

// ---- fused G1+G2: grid (24,1,16) ----
__global__ __launch_bounds__(512, 2) void k_proj8(
    const unsigned short* __restrict__ wpg, const unsigned short* __restrict__ xt,
    const unsigned short* __restrict__ thw,
    unsigned short* __restrict__ phg, unsigned short* __restrict__ tht,
    const float* __restrict__ pgbias, const float* __restrict__ theta_b) {
  __shared__ __align__(16) char lds[131072];
  const int x = blockIdx.x, z = blockIdx.z;
  const size_t sXT = (size_t)2048 * 512, sPG = (size_t)512 * 2048, sTH = (size_t)2048 * 256;
  if (x < 16) {
    gemm256_body<1, false>(wpg, xt + z * sXT, phg + z * sPG, 2048, 512, 0, 8,
                           (x >> 3) * 256, (x & 7) * 256, pgbias, 1.f, lds);
  } else {
    const int u = x - 16;
    gemm256_body<2, false>(xt + z * sXT, thw, tht + z * sTH, 256, 512, 0, 8,
                           u * 256, 0, theta_b, 1.f, lds);
  }
}

// ---- G3: pbuf[split][b][c'][c] partials (16 splits of K=128), grid (16,1,16) ----
__global__ __launch_bounds__(512, 2) void k_part8(const unsigned short* __restrict__ phg,
                                                  float* __restrict__ pbuf) {
  __shared__ __align__(16) char lds[131072];
  const int split = blockIdx.x, b = blockIdx.z;
  const size_t sPG = (size_t)512 * 2048;
  gemm256_body<0, true>(phg + (size_t)b * sPG, phg + (size_t)b * sPG + (size_t)256 * 2048,
                        pbuf + ((size_t)split * 16 + b) * 65536, 256,
                        2048, split * 128, 2, 0, 0, nullptr, 1.f, lds);
}

// ---- G5: w[co,n] = sum_c' mmat[co,c'] tht[n,c'] + W_b[co], grid (16,1,16) ----
__global__ __launch_bounds__(512, 2) void k_gemm58(const unsigned short* __restrict__ mmat,
                                                   const unsigned short* __restrict__ tht,
                                                   unsigned short* __restrict__ wbuf,
                                                   const float* __restrict__ W_b) {
  __shared__ __align__(16) char lds[131072];
  const int x = blockIdx.x, z = blockIdx.z;
  const size_t sMM = (size_t)512 * 256, sTH = (size_t)2048 * 256, sW = (size_t)512 * 2048;
  gemm256_body<1, false>(mmat + z * sMM, tht + z * sTH, wbuf + z * sW, 2048, 256, 0, 4,
                         (x >> 3) * 256, (x & 7) * 256, W_b, 1.f, lds);
}

// ---- G4: mmat[b][co,c'] = (1/N) sum_ch ww[co,ch] (sum over 16 split-planes of pbuf) ----
__global__ __launch_bounds__(256) void k_gemm_f32b(const unsigned short* __restrict__ ww,
                                                   const float* __restrict__ pbuf,
                                                   unsigned short* __restrict__ mmat) {
  __shared__ __align__(16) __bf16 At[64 * 32];
  __shared__ __align__(16) __bf16 Bt[64 * 32];
  const int t = threadIdx.x;
  const int b = blockIdx.z;
  const int col0 = blockIdx.x * 64;
  const int row0 = blockIdx.y * 64;
  const size_t SSTR = (size_t)16 * 65536;
  const float* Bz = pbuf + (size_t)b * 65536;
  const int w = t >> 6, lane = t & 63;
  const int l16 = lane & 15, lq = lane >> 4;
  const int wrow0 = (w >> 1) * 32, wcol0 = (w & 1) * 32;

  floatx4 acc[2][2];
#pragma unroll
  for (int m = 0; m < 2; ++m)
#pragma unroll
    for (int n = 0; n < 2; ++n) acc[m][n] = (floatx4){0.f, 0.f, 0.f, 0.f};

  for (int kt = 0; kt < 8; ++kt) {
    __syncthreads();
    {
      int r = t >> 2, kq = t & 3;
      gload_lds16(ww + (size_t)(row0 + r) * 256 + (kt << 5) + (kq << 3), &At[t * 8]);
    }
    {
      int r = t >> 2, kq = t & 3;
      const float* src = Bz + (size_t)(col0 + r) * 256 + (kt << 5) + (kq << 3);
      float4 a = *(const float4*)src;
      float4 c = *(const float4*)(src + 4);
#pragma unroll
      for (int s = 1; s < 16; ++s) {
        float4 a2 = *(const float4*)(src + s * SSTR);
        float4 c2 = *(const float4*)(src + s * SSTR + 4);
        a.x += a2.x; a.y += a2.y; a.z += a2.z; a.w += a2.w;
        c.x += c2.x; c.y += c2.y; c.z += c2.z; c.w += c2.w;
      }
      union { unsigned short s[8]; bf16x8 v; } pk;
      pk.s[0] = f2bf(a.x); pk.s[1] = f2bf(a.y); pk.s[2] = f2bf(a.z); pk.s[3] = f2bf(a.w);
      pk.s[4] = f2bf(c.x); pk.s[5] = f2bf(c.y); pk.s[6] = f2bf(c.z); pk.s[7] = f2bf(c.w);
      *(bf16x8*)&Bt[t * 8] = pk.v;
    }
    __syncthreads();
    bf16x8 af[2], bq[2];
#pragma unroll
    for (int m = 0; m < 2; ++m)
      af[m] = *(const bf16x8*)&At[(wrow0 + m * 16 + l16) * 32 + lq * 8];
#pragma unroll
    for (int n = 0; n < 2; ++n)
      bq[n] = *(const bf16x8*)&Bt[(wcol0 + n * 16 + l16) * 32 + lq * 8];
#pragma unroll
    for (int m = 0; m < 2; ++m)
#pragma unroll
      for (int n = 0; n < 2; ++n)
        acc[m][n] = __builtin_amdgcn_mfma_f32_16x16x32_bf16(af[m], bq[n], acc[m][n], 0, 0, 0);
  }
  unsigned short* Cz = mmat + (size_t)b * 512 * 256;
  const float scale = 1.f / 2048.f;
#pragma unroll
  for (int m = 0; m < 2; ++m)
#pragma unroll
    for (int n = 0; n < 2; ++n)
#pragma unroll
      for (int r = 0; r < 4; ++r) {
        int gr = row0 + wrow0 + m * 16 + lq * 4 + r;
        int gc = col0 + wcol0 + n * 16 + l16;
        Cz[(size_t)gr * 256 + gc] = f2bf(acc[m][n][r] * scale);
      }
}

// ---- BN stats ----
__global__ __launch_bounds__(256) void k_bnstats(const unsigned short* __restrict__ w,
                                                 const float* __restrict__ gamma,
                                                 const float* __restrict__ beta,
                                                 float* __restrict__ scale,
                                                 float* __restrict__ shift) {
  const int c = blockIdx.x, t = threadIdx.x;
  float s = 0.f, ss = 0.f;
  for (int b = 0; b < 16; ++b) {
    const unsigned short* p = w + ((size_t)b * 512 + c) * 2048 + t * 8;
    uint4 v = *(const uint4*)p;
    unsigned u[4] = {v.x, v.y, v.z, v.w};
#pragma unroll
    for (int j = 0; j < 4; ++j) {
      union { unsigned q; float f; } a, bb;
      a.q = u[j] << 16;
      bb.q = u[j] & 0xFFFF0000u;
      s += a.f + bb.f;
      ss += a.f * a.f + bb.f * bb.f;
    }
  }
#pragma unroll
  for (int off = 32; off; off >>= 1) {
    s += __shfl_down(s, off);
    ss += __shfl_down(ss, off);
  }
  __shared__ float ls[4], lss[4];
  if ((t & 63) == 0) { ls[t >> 6] = s; lss[t >> 6] = ss; }
  __syncthreads();
  if (t == 0) {
    float S = ls[0] + ls[1] + ls[2] + ls[3];
    float SS = lss[0] + lss[1] + lss[2] + lss[3];
    const float inv = 1.f / 32768.f;
    float mean = S * inv;
    float var = SS * inv - mean * mean;
    float rs = rsqrtf(var + 1e-5f);
    float sc = gamma[c] * rs;
    scale[c] = sc;
    shift[c] = beta[c] - mean * sc;
  }
}

// ---- finalize: out = w*scale[c] + shift[c] + x ----
__global__ __launch_bounds__(256) void k_final(const unsigned short* __restrict__ w,
                                               const float* __restrict__ x,
                                               const float* __restrict__ scale,
                                               const float* __restrict__ shift,
                                               float* __restrict__ out) {
  const size_t total4 = (size_t)16 * 512 * 2048 / 4;
  size_t stride = (size_t)gridDim.x * 256;
  for (size_t i = (size_t)blockIdx.x * 256 + threadIdx.x; i < total4; i += stride) {
    size_t e = i * 4;
    int c = (int)((e >> 11) & 511);
    float sc = scale[c], sh = shift[c];
    uint2 wv = *(const uint2*)(w + e);
    float4 xv = *(const float4*)(x + e);
    float4 o;
    union { unsigned q; float f; } a;
    a.q = wv.x << 16;          o.x = a.f * sc + sh + xv.x;
    a.q = wv.x & 0xFFFF0000u;  o.y = a.f * sc + sh + xv.y;
    a.q = wv.y << 16;          o.z = a.f * sc + sh + xv.z;
    a.q = wv.y & 0xFFFF0000u;  o.w = a.f * sc + sh + xv.w;
    *(float4*)(out + e) = o;
  }
}

extern "C" void kernel_launch(void* const* d_in, const int* in_sizes, int n_in,
                              void* d_out, int out_size, void* d_ws, size_t ws_size,
                              hipStream_t stream) {
  const float* x       = (const float*)d_in[0];
  const float* theta_w = (const float*)d_in[1];
  const float* theta_b = (const float*)d_in[2];
  const float* phi_w   = (const float*)d_in[3];
  const float* phi_b   = (const float*)d_in[4];
  const float* g_w     = (const float*)d_in[5];
  const float* g_b     = (const float*)d_in[6];
  const float* W_w     = (const float*)d_in[7];
  const float* W_b     = (const float*)d_in[8];
  const float* gamma   = (const float*)d_in[9];
  const float* beta    = (const float*)d_in[10];
  float* out = (float*)d_out;

  char* ws = (char*)d_ws;
  size_t off = 0;
  auto alloc = [&](size_t bytes) {
    char* p = ws + off;
    off = (off + bytes + 255) & ~(size_t)255;
    return p;
  };
  unsigned short* xt    = (unsigned short*)alloc((size_t)16 * 2048 * 512 * 2);
  unsigned short* phg   = (unsigned short*)alloc((size_t)16 * 512 * 2048 * 2);
  unsigned short* tht   = (unsigned short*)alloc((size_t)16 * 2048 * 256 * 2);
  float*          pbuf  = (float*)alloc((size_t)16 * 16 * 256 * 256 * 4);  // [split][b][256][256]
  unsigned short* mmat  = (unsigned short*)alloc((size_t)16 * 512 * 256 * 2);
  unsigned short* wbuf  = (unsigned short*)alloc((size_t)16 * 512 * 2048 * 2);
  unsigned short* wpg   = (unsigned short*)alloc((size_t)512 * 512 * 2);
  unsigned short* thw   = (unsigned short*)alloc((size_t)256 * 512 * 2);
  unsigned short* ww    = (unsigned short*)alloc((size_t)512 * 256 * 2);
  float* pgbias         = (float*)alloc(512 * 4);
  float* scalev         = (float*)alloc(512 * 4);
  float* shiftv         = (float*)alloc(512 * 4);
  (void)ws_size; (void)in_sizes; (void)n_in; (void)out_size;

  k_transpose<<<dim3(32, 8, 17), 256, 0, stream>>>(x, xt, phi_w, g_w, theta_w, W_w,
                                                   phi_b, g_b, wpg, thw, ww, pgbias);
  k_proj8<<<dim3(24, 1, 16), 512, 0, stream>>>(wpg, xt, thw, phg, tht, pgbias, theta_b);
  k_part8<<<dim3(16, 1, 16), 512, 0, stream>>>(phg, pbuf);
  k_gemm_f32b<<<dim3(4, 8, 16), 256, 0, stream>>>(ww, pbuf, mmat);
  k_gemm58<<<dim3(16, 1, 16), 512, 0, stream>>>(mmat, tht, wbuf, W_b);
  k_bnstats<<<512, 256, 0, stream>>>(wbuf, gamma, beta, scalev, shiftv);
  k_final<<<4096, 256, 0, stream>>>(wbuf, x, scalev, shiftv, out);
}

// Round 9
// 244.688 us; speedup vs baseline: 1.1556x; 1.1556x over previous
//
#include <hip/hip_runtime.h>

typedef __bf16 bf16x8 __attribute__((ext_vector_type(8)));
typedef float floatx4 __attribute__((ext_vector_type(4)));

#define DEVI __device__ __forceinline__

DEVI unsigned short f2bf(float f) {
  union { float f; unsigned u; } v; v.f = f;
  unsigned r = v.u + 0x7FFFu + ((v.u >> 16) & 1u);
  return (unsigned short)(r >> 16);
}

DEVI void gload_lds16(const void* g, void* l) {
  __builtin_amdgcn_global_load_lds((const __attribute__((address_space(1))) void*)g,
                                   (__attribute__((address_space(3))) void*)l,
                                   16, 0, 0);
}

// ---- transpose-convert x[B,512,2048] f32 -> xt[B,2048,512] bf16 ; z==16 slice does weight prep ----
__global__ __launch_bounds__(256) void k_transpose(
    const float* __restrict__ x, unsigned short* __restrict__ xt,
    const float* __restrict__ phi_w, const float* __restrict__ g_w,
    const float* __restrict__ theta_w, const float* __restrict__ W_w,
    const float* __restrict__ phi_b, const float* __restrict__ g_b,
    unsigned short* __restrict__ wpg, unsigned short* __restrict__ thw,
    unsigned short* __restrict__ ww, float* __restrict__ pgbias) {
  const int t = threadIdx.x;
  if (blockIdx.z == 16) {
    const int T0 = 512 * 512, T1 = T0 + 256 * 512, T2 = T1 + 512 * 256, T3 = T2 + 512;
    int base = (blockIdx.y * 32 + blockIdx.x) * 256 + t;
    for (int i = base; i < T3; i += 65536) {
      if (i < T0) {
        int o = i >> 9, c = i & 511;
        float v = (o < 256) ? phi_w[o * 512 + c] : g_w[(o - 256) * 512 + c];
        wpg[i] = f2bf(v);
      } else if (i < T1) {
        int j = i - T0; thw[j] = f2bf(theta_w[j]);
      } else if (i < T2) {
        int j = i - T1; ww[j] = f2bf(W_w[j]);
      } else {
        int o = i - T2; pgbias[o] = (o < 256) ? phi_b[o] : g_b[o - 256];
      }
    }
    return;
  }
  __shared__ float tile[64][65];
  const int b = blockIdx.z, c0 = blockIdx.y * 64, n0 = blockIdx.x * 64;
  const float* xb = x + (size_t)b * 512 * 2048;
#pragma unroll
  for (int i = 0; i < 16; ++i) {
    int lin = i * 256 + t;
    int lc = lin >> 6, ln = lin & 63;
    tile[lc][ln] = xb[(size_t)(c0 + lc) * 2048 + (n0 + ln)];
  }
  __syncthreads();
  unsigned short* xtb = xt + (size_t)b * 2048 * 512;
#pragma unroll
  for (int i = 0; i < 16; ++i) {
    int lin = i * 256 + t;
    int ln = lin >> 6, lc = lin & 63;
    xtb[(size_t)(n0 + ln) * 512 + (c0 + lc)] = f2bf(tile[lc][ln]);
  }
}

// ---- shared GEMM tile body: C[i,j] = scale*sum_k A[i,k]B[j,k] (+bias); BK=64, swizzled LDS ----
// EPI: 0 none, 1 +bias[row], 2 +bias[col]. BNS: per-block BN partials (sum/sumsq per row)
// into bnpart[row][slot] / bnpart[131072 + row*256 + slot]  (no atomics).
template <int BM, int BN, int EPI, bool BNS>
DEVI void gemm_body(const unsigned short* __restrict__ Az,
                    const unsigned short* __restrict__ Bz,
                    unsigned short* __restrict__ Cz, int N, int K,
                    int row0, int col0,
                    const float* __restrict__ bias, float scale,
                    __bf16* At, __bf16* Bt,
                    float* __restrict__ bnpart, int bnslot) {
  constexpr int WM = BM / 2, WN = BN / 2;
  constexpr int FM = WM / 16, FN = WN / 16;
  const int t = threadIdx.x;
  const int w = t >> 6, lane = t & 63;
  const int l16 = lane & 15, lq = lane >> 4;
  const int wrow0 = (w >> 1) * WM, wcol0 = (w & 1) * WN;
  const int xorb = (l16 & 7) << 4;
  const int aoff0 = (wrow0 + l16) * 128;
  const int boff0 = (wcol0 + l16) * 128;

  floatx4 acc[FM][FN];
#pragma unroll
  for (int m = 0; m < FM; ++m)
#pragma unroll
    for (int n = 0; n < FN; ++n) acc[m][n] = (floatx4){0.f, 0.f, 0.f, 0.f};

  const int kt_end = K >> 6;
  for (int kt = 0; kt < kt_end; ++kt) {
    __syncthreads();
#pragma unroll
    for (int i = 0; i < BM * 8 / 256; ++i) {
      int ch = i * 256 + t;
      int r = ch >> 3;
      int sc = ((((ch & 7) << 4) ^ ((r & 7) << 4)) >> 1);
      gload_lds16(Az + (size_t)(row0 + r) * K + (kt << 6) + sc, &At[ch * 8]);
    }
#pragma unroll
    for (int i = 0; i < BN * 8 / 256; ++i) {
      int ch = i * 256 + t;
      int r = ch >> 3;
      int sc = ((((ch & 7) << 4) ^ ((r & 7) << 4)) >> 1);
      gload_lds16(Bz + (size_t)(col0 + r) * K + (kt << 6) + sc, &Bt[ch * 8]);
    }
    __syncthreads();

#pragma unroll
    for (int kk = 0; kk < 2; ++kk) {
      const int ck = ((kk << 6) + (lq << 4)) ^ xorb;
      bf16x8 af[FM], bq[FN];
#pragma unroll
      for (int m = 0; m < FM; ++m)
        af[m] = *(const bf16x8*)((const char*)At + aoff0 + m * 2048 + ck);
#pragma unroll
      for (int n = 0; n < FN; ++n)
        bq[n] = *(const bf16x8*)((const char*)Bt + boff0 + n * 2048 + ck);
#pragma unroll
      for (int m = 0; m < FM; ++m)
#pragma unroll
        for (int n = 0; n < FN; ++n)
          acc[m][n] = __builtin_amdgcn_mfma_f32_16x16x32_bf16(af[m], bq[n], acc[m][n], 0, 0, 0);
    }
  }

  float rs[FM][4], rss[FM][4];
  if (BNS) {
#pragma unroll
    for (int m = 0; m < FM; ++m)
#pragma unroll
      for (int r = 0; r < 4; ++r) { rs[m][r] = 0.f; rss[m][r] = 0.f; }
  }

#pragma unroll
  for (int m = 0; m < FM; ++m)
#pragma unroll
    for (int n = 0; n < FN; ++n) {
      int gc = col0 + wcol0 + n * 16 + l16;
      float bc = (EPI == 2) ? bias[gc] : 0.f;
#pragma unroll
      for (int r = 0; r < 4; ++r) {
        int gr = row0 + wrow0 + m * 16 + lq * 4 + r;
        float v = acc[m][n][r] * scale;
        if (EPI == 1) v += bias[gr];
        if (EPI == 2) v += bc;
        if (BNS) { rs[m][r] += v; rss[m][r] += v * v; }
        Cz[(size_t)gr * N + gc] = f2bf(v);
      }
    }

  if (BNS) {
    // reuse At LDS space for the block-level combine (all reads of At are done)
    __syncthreads();
    float* bnl = (float*)At;  // [128 rows][2 col-halves] x 2 planes = 2 KB
#pragma unroll
    for (int m = 0; m < FM; ++m)
#pragma unroll
      for (int r = 0; r < 4; ++r) {
        float s = rs[m][r], ss = rss[m][r];
        s += __shfl_xor(s, 1); ss += __shfl_xor(ss, 1);
        s += __shfl_xor(s, 2); ss += __shfl_xor(ss, 2);
        s += __shfl_xor(s, 4); ss += __shfl_xor(ss, 4);
        s += __shfl_xor(s, 8); ss += __shfl_xor(ss, 8);
        if (l16 == 0) {
          int rl = wrow0 + m * 16 + lq * 4 + r;  // 0..BM-1 local row
          bnl[rl * 2 + (w & 1)] = s;
          bnl[2 * BM + rl * 2 + (w & 1)] = ss;
        }
      }
    __syncthreads();
    if (t < BM) {
      float s = bnl[t * 2] + bnl[t * 2 + 1];
      float ss = bnl[2 * BM + t * 2] + bnl[2 * BM + t * 2 + 1];
      bnpart[(size_t)(row0 + t) * 256 + bnslot] = s;
      bnpart[(size_t)131072 + (size_t)(row0 + t) * 256 + bnslot] = ss;
    }
  }
}

// ---- fused G1+G2: grid (96, 1, 16). tid<64: PhG tile; tid>=64: Th^T tile ----
__global__ __launch_bounds__(256) void k_proj(
    const unsigned short* __restrict__ wpg, const unsigned short* __restrict__ xt,
    const unsigned short* __restrict__ thw,
    unsigned short* __restrict__ phg, unsigned short* __restrict__ tht,
    const float* __restrict__ pgbias, const float* __restrict__ theta_b) {
  __shared__ __align__(16) __bf16 At[128 * 64];
  __shared__ __align__(16) __bf16 Bt[128 * 64];
  const int z = blockIdx.z, tid = blockIdx.x;
  const size_t sXT = (size_t)2048 * 512;
  const size_t sPG = (size_t)512 * 2048;
  const size_t sTH = (size_t)2048 * 256;
  if (tid < 64) {
    const int col = tid & 15, row = tid >> 4;
    gemm_body<128, 128, 1, false>(wpg, xt + z * sXT, phg + z * sPG, 2048, 512,
                                  row * 128, col * 128, pgbias, 1.f, At, Bt, nullptr, 0);
  } else {
    const int u = tid - 64;
    const int col = u & 1, row = u >> 1;
    gemm_body<128, 128, 2, false>(xt + z * sXT, thw, tht + z * sTH, 256, 512,
                                  row * 128, col * 128, theta_b, 1.f, At, Bt, nullptr, 0);
  }
}

// ---- G5 with fused BN partials: grid (16, 4, 16) ----
__global__ __launch_bounds__(256) void k_gemm5(
    const unsigned short* __restrict__ mmat, const unsigned short* __restrict__ tht,
    unsigned short* __restrict__ wbuf, const float* __restrict__ W_b,
    float* __restrict__ bnpart) {
  __shared__ __align__(16) __bf16 At[128 * 64];
  __shared__ __align__(16) __bf16 Bt[128 * 64];
  const int z = blockIdx.z;
  const size_t sMM = (size_t)512 * 256, sTH = (size_t)2048 * 256, sW = (size_t)512 * 2048;
  gemm_body<128, 128, 1, true>(mmat + z * sMM, tht + z * sTH, wbuf + z * sW,
                               2048, 256, blockIdx.y * 128, blockIdx.x * 128,
                               W_b, 1.f, At, Bt, bnpart, z * 16 + blockIdx.x);
}

// ---- G3: pbuf[s][b][c'][c] = partial_{K-slice s} sum_n ph[c',n] g[c,n]  (NO atomics) ----
// grid (16, 1, 16): x decodes (split 2b | tr 1b | tc 1b); 128x128 tile, 4 waves, 8 BK-64 steps.
__global__ __launch_bounds__(256) void k_gemm_part(const unsigned short* __restrict__ phg,
                                                   float* __restrict__ pbuf) {
  __shared__ __align__(16) __bf16 At[128 * 64];
  __shared__ __align__(16) __bf16 Bt[128 * 64];
  const int t = threadIdx.x;
  const int tid = blockIdx.x, b = blockIdx.z;
  const int split = tid >> 2, tr = (tid >> 1) & 1, tc = tid & 1;
  const int row0 = tr * 128, col0 = tc * 128;
  const size_t sPG = (size_t)512 * 2048;
  const unsigned short* Az = phg + (size_t)b * sPG + (size_t)row0 * 2048;
  const unsigned short* Bz = phg + (size_t)b * sPG + (size_t)(256 + col0) * 2048;
  const int w = t >> 6, lane = t & 63;
  const int l16 = lane & 15, lq = lane >> 4;
  const int wrow0 = (w >> 1) * 64, wcol0 = (w & 1) * 64;
  const int xorb = (l16 & 7) << 4;
  const int aoff0 = (wrow0 + l16) * 128;
  const int boff0 = (wcol0 + l16) * 128;

  floatx4 acc[4][4];
#pragma unroll
  for (int m = 0; m < 4; ++m)
#pragma unroll
    for (int n = 0; n < 4; ++n) acc[m][n] = (floatx4){0.f, 0.f, 0.f, 0.f};

  for (int kt8 = 0; kt8 < 8; ++kt8) {
    const int kt = split * 8 + kt8;
    __syncthreads();
#pragma unroll
    for (int i = 0; i < 4; ++i) {
      int ch = i * 256 + t;
      int r = ch >> 3;
      int sc = ((((ch & 7) << 4) ^ ((r & 7) << 4)) >> 1);
      gload_lds16(Az + (size_t)r * 2048 + (kt << 6) + sc, &At[ch * 8]);
    }
#pragma unroll
    for (int i = 0; i < 4; ++i) {
      int ch = i * 256 + t;
      int r = ch >> 3;
      int sc = ((((ch & 7) << 4) ^ ((r & 7) << 4)) >> 1);
      gload_lds16(Bz + (size_t)r * 2048 + (kt << 6) + sc, &Bt[ch * 8]);
    }
    __syncthreads();
#pragma unroll
    for (int kk = 0; kk < 2; ++kk) {
      const int ck = ((kk << 6) + (lq << 4)) ^ xorb;
      bf16x8 af[4], bq[4];
#pragma unroll
      for (int m = 0; m < 4; ++m)
        af[m] = *(const bf16x8*)((const char*)At + aoff0 + m * 2048 + ck);
#pragma unroll
      for (int n = 0; n < 4; ++n)
        bq[n] = *(const bf16x8*)((const char*)Bt + boff0 + n * 2048 + ck);
#pragma unroll
      for (int m = 0; m < 4; ++m)
#pragma unroll
        for (int n = 0; n < 4; ++n)
          acc[m][n] = __builtin_amdgcn_mfma_f32_16x16x32_bf16(af[m], bq[n], acc[m][n], 0, 0, 0);
    }
  }
  float* outp = pbuf + ((size_t)split * 16 + b) * 65536;
#pragma unroll
  for (int m = 0; m < 4; ++m)
#pragma unroll
    for (int n = 0; n < 4; ++n)
#pragma unroll
      for (int r = 0; r < 4; ++r) {
        int gr = row0 + wrow0 + m * 16 + lq * 4 + r;
        int gc = col0 + wcol0 + n * 16 + l16;
        outp[(size_t)gr * 256 + gc] = acc[m][n][r];
      }
}

// ---- G4: mmat[b][co,c'] = (1/N) sum_ch ww[co,ch] (sum_s pbuf[s][b][c',ch]) ----
__global__ __launch_bounds__(256) void k_gemm_f32b(const unsigned short* __restrict__ ww,
                                                   const float* __restrict__ pbuf,
                                                   unsigned short* __restrict__ mmat) {
  __shared__ __align__(16) __bf16 At[64 * 32];
  __shared__ __align__(16) __bf16 Bt[64 * 32];
  const int t = threadIdx.x;
  const int b = blockIdx.z;
  const int col0 = blockIdx.x * 64;
  const int row0 = blockIdx.y * 64;
  const size_t SSTR = (size_t)16 * 65536;
  const float* Bz = pbuf + (size_t)b * 65536;
  const int w = t >> 6, lane = t & 63;
  const int l16 = lane & 15, lq = lane >> 4;
  const int wrow0 = (w >> 1) * 32, wcol0 = (w & 1) * 32;

  floatx4 acc[2][2];
#pragma unroll
  for (int m = 0; m < 2; ++m)
#pragma unroll
    for (int n = 0; n < 2; ++n) acc[m][n] = (floatx4){0.f, 0.f, 0.f, 0.f};

  for (int kt = 0; kt < 8; ++kt) {
    __syncthreads();
    {
      int r = t >> 2, kq = t & 3;
      gload_lds16(ww + (size_t)(row0 + r) * 256 + (kt << 5) + (kq << 3), &At[t * 8]);
    }
    {
      int r = t >> 2, kq = t & 3;
      const float* src = Bz + (size_t)(col0 + r) * 256 + (kt << 5) + (kq << 3);
      float4 a = *(const float4*)src;
      float4 c = *(const float4*)(src + 4);
#pragma unroll
      for (int s = 1; s < 4; ++s) {
        float4 a2 = *(const float4*)(src + s * SSTR);
        float4 c2 = *(const float4*)(src + s * SSTR + 4);
        a.x += a2.x; a.y += a2.y; a.z += a2.z; a.w += a2.w;
        c.x += c2.x; c.y += c2.y; c.z += c2.z; c.w += c2.w;
      }
      union { unsigned short s[8]; bf16x8 v; } pk;
      pk.s[0] = f2bf(a.x); pk.s[1] = f2bf(a.y); pk.s[2] = f2bf(a.z); pk.s[3] = f2bf(a.w);
      pk.s[4] = f2bf(c.x); pk.s[5] = f2bf(c.y); pk.s[6] = f2bf(c.z); pk.s[7] = f2bf(c.w);
      *(bf16x8*)&Bt[t * 8] = pk.v;
    }
    __syncthreads();
    bf16x8 af[2], bq[2];
#pragma unroll
    for (int m = 0; m < 2; ++m)
      af[m] = *(const bf16x8*)&At[(wrow0 + m * 16 + l16) * 32 + lq * 8];
#pragma unroll
    for (int n = 0; n < 2; ++n)
      bq[n] = *(const bf16x8*)&Bt[(wcol0 + n * 16 + l16) * 32 + lq * 8];
#pragma unroll
    for (int m = 0; m < 2; ++m)
#pragma unroll
      for (int n = 0; n < 2; ++n)
        acc[m][n] = __builtin_amdgcn_mfma_f32_16x16x32_bf16(af[m], bq[n], acc[m][n], 0, 0, 0);
  }
  unsigned short* Cz = mmat + (size_t)b * 512 * 256;
  const float scale = 1.f / 2048.f;
#pragma unroll
  for (int m = 0; m < 2; ++m)
#pragma unroll
    for (int n = 0; n < 2; ++n)
#pragma unroll
      for (int r = 0; r < 4; ++r) {
        int gr = row0 + wrow0 + m * 16 + lq * 4 + r;
        int gc = col0 + wcol0 + n * 16 + l16;
        Cz[(size_t)gr * 256 + gc] = f2bf(acc[m][n][r] * scale);
      }
}

// ---- BN finalize (tiny): reduce bnpart[512][256] x2 -> scale/shift ----
__global__ __launch_bounds__(256) void k_bnlite(const float* __restrict__ bnpart,
                                                const float* __restrict__ gamma,
                                                const float* __restrict__ beta,
                                                float* __restrict__ scale,
                                                float* __restrict__ shift) {
  const int c = blockIdx.x, t = threadIdx.x;
  float s = bnpart[(size_t)c * 256 + t];
  float ss = bnpart[(size_t)131072 + (size_t)c * 256 + t];
#pragma unroll
  for (int off = 32; off; off >>= 1) {
    s += __shfl_down(s, off);
    ss += __shfl_down(ss, off);
  }
  __shared__ float ls[4], lss[4];
  if ((t & 63) == 0) { ls[t >> 6] = s; lss[t >> 6] = ss; }
  __syncthreads();
  if (t == 0) {
    float S = ls[0] + ls[1] + ls[2] + ls[3];
    float SS = lss[0] + lss[1] + lss[2] + lss[3];
    const float inv = 1.f / 32768.f;
    float mean = S * inv;
    float var = SS * inv - mean * mean;
    float rs = rsqrtf(var + 1e-5f);
    float sc = gamma[c] * rs;
    scale[c] = sc;
    shift[c] = beta[c] - mean * sc;
  }
}

// ---- finalize: out = w*scale[c] + shift[c] + x ----
__global__ __launch_bounds__(256) void k_final(const unsigned short* __restrict__ w,
                                               const float* __restrict__ x,
                                               const float* __restrict__ scale,
                                               const float* __restrict__ shift,
                                               float* __restrict__ out) {
  const size_t total4 = (size_t)16 * 512 * 2048 / 4;
  size_t stride = (size_t)gridDim.x * 256;
  for (size_t i = (size_t)blockIdx.x * 256 + threadIdx.x; i < total4; i += stride) {
    size_t e = i * 4;
    int c = (int)((e >> 11) & 511);
    float sc = scale[c], sh = shift[c];
    uint2 wv = *(const uint2*)(w + e);
    float4 xv = *(const float4*)(x + e);
    float4 o;
    union { unsigned q; float f; } a;
    a.q = wv.x << 16;          o.x = a.f * sc + sh + xv.x;
    a.q = wv.x & 0xFFFF0000u;  o.y = a.f * sc + sh + xv.y;
    a.q = wv.y << 16;          o.z = a.f * sc + sh + xv.z;
    a.q = wv.y & 0xFFFF0000u;  o.w = a.f * sc + sh + xv.w;
    *(float4*)(out + e) = o;
  }
}

extern "C" void kernel_launch(void* const* d_in, const int* in_sizes, int n_in,
                              void* d_out, int out_size, void* d_ws, size_t ws_size,
                              hipStream_t stream) {
  const float* x       = (const float*)d_in[0];
  const float* theta_w = (const float*)d_in[1];
  const float* theta_b = (const float*)d_in[2];
  const float* phi_w   = (const float*)d_in[3];
  const float* phi_b   = (const float*)d_in[4];
  const float* g_w     = (const float*)d_in[5];
  const float* g_b     = (const float*)d_in[6];
  const float* W_w     = (const float*)d_in[7];
  const float* W_b     = (const float*)d_in[8];
  const float* gamma   = (const float*)d_in[9];
  const float* beta    = (const float*)d_in[10];
  float* out = (float*)d_out;

  char* ws = (char*)d_ws;
  size_t off = 0;
  auto alloc = [&](size_t bytes) {
    char* p = ws + off;
    off = (off + bytes + 255) & ~(size_t)255;
    return p;
  };
  unsigned short* xt    = (unsigned short*)alloc((size_t)16 * 2048 * 512 * 2);
  unsigned short* phg   = (unsigned short*)alloc((size_t)16 * 512 * 2048 * 2);
  unsigned short* tht   = (unsigned short*)alloc((size_t)16 * 2048 * 256 * 2);
  float*          pbuf  = (float*)alloc((size_t)4 * 16 * 256 * 256 * 4);   // split-K partials
  unsigned short* mmat  = (unsigned short*)alloc((size_t)16 * 512 * 256 * 2);
  unsigned short* wbuf  = (unsigned short*)alloc((size_t)16 * 512 * 2048 * 2);
  float*          bnpart= (float*)alloc((size_t)2 * 512 * 256 * 4);        // BN partials (1 MB)
  unsigned short* wpg   = (unsigned short*)alloc((size_t)512 * 512 * 2);
  unsigned short* thw   = (unsigned short*)alloc((size_t)256 * 512 * 2);
  unsigned short* ww    = (unsigned short*)alloc((size_t)512 * 256 * 2);
  float* pgbias         = (float*)alloc(512 * 4);
  float* scalev         = (float*)alloc(512 * 4);
  float* shiftv         = (float*)alloc(512 * 4);
  (void)ws_size; (void)in_sizes; (void)n_in; (void)out_size;

  k_transpose<<<dim3(32, 8, 17), 256, 0, stream>>>(x, xt, phi_w, g_w, theta_w, W_w,
                                                   phi_b, g_b, wpg, thw, ww, pgbias);

  // G1+G2 fused: PhG and Th^T from xt
  k_proj<<<dim3(96, 1, 16), 256, 0, stream>>>(wpg, xt, thw, phg, tht, pgbias, theta_b);
  // G3: pbuf[s][b] = K-slice partials of Ph·G^T (4 splits, no atomics)
  k_gemm_part<<<dim3(16, 1, 16), 256, 0, stream>>>(phg, pbuf);
  // G4: mmat[co,c'] = (1/N) sum_ch ww[co,ch] (sum_s pbuf[s][c',ch])
  k_gemm_f32b<<<dim3(4, 8, 16), 256, 0, stream>>>(ww, pbuf, mmat);
  // G5: w[co,n] = sum_c' mmat[co,c'] tht[n,c'] + W_b[co], with fused BN partials
  k_gemm5<<<dim3(16, 4, 16), 256, 0, stream>>>(mmat, tht, wbuf, W_b, bnpart);

  k_bnlite<<<512, 256, 0, stream>>>(bnpart, gamma, beta, scalev, shiftv);
  k_final<<<4096, 256, 0, stream>>>(wbuf, x, scalev, shiftv, out);
}